// Round 8
// baseline (99.728 us; speedup 1.0000x reference)
//
#include <hip/hip_runtime.h>

#define B_ 96
#define S_ 128
#define C_ 141
#define D_ 768
#define K_ 1536   // 2*D
#define M_ (B_*S_)   // 12288 (worst case)
#define N_ 1536   // 2*D

typedef unsigned short u16;
typedef __bf16 bf16x8 __attribute__((ext_vector_type(8)));
typedef float f32x4 __attribute__((ext_vector_type(4)));
typedef unsigned int u32x4 __attribute__((ext_vector_type(4)));

__device__ __forceinline__ u16 f2bf(float x) {
  unsigned int u = __float_as_uint(x);
  u = u + 0x7fffu + ((u >> 16) & 1u);   // RNE
  return (u16)(u >> 16);
}

__device__ __forceinline__ void gload_lds16(const void* g, void* l) {
  __builtin_amdgcn_global_load_lds(
      (const __attribute__((address_space(1))) unsigned int*)g,
      (__attribute__((address_space(3))) unsigned int*)l, 16, 0, 0);
}

__device__ __forceinline__ unsigned lds_off(const void* p) {
  return (unsigned)(size_t)(const __attribute__((address_space(3))) char*)p;
}

__device__ __forceinline__ bf16x8 ldsr128(unsigned a) {
  u32x4 d;
  asm volatile("ds_read_b128 %0, %1" : "=v"(d) : "v"(a));
  return __builtin_bit_cast(bf16x8, d);
}

// ---- tokmap + per-batch used-token rank (one block per batch, 192 thr) ----
__global__ void tokmap_rank_kernel(const int* __restrict__ om,
                                   int* __restrict__ tokmap,
                                   int* __restrict__ cidx,
                                   int* __restrict__ cnt) {
  __shared__ int st[C_];
  __shared__ int c0;
  const int b = blockIdx.x;
  const int t = threadIdx.x;   // 0..191
  int s = 0, e = 0;
  if (t < S_) {
    s = om[(b * S_ + t) * 2 + 0];
    e = om[(b * S_ + t) * 2 + 1];
  }
  if (t < C_) st[t] = -1;
  __syncthreads();
  if (t < S_) {
    for (int c = s; c < e; ++c) st[c] = t;   // disjoint -> race-free
  }
  __syncthreads();
  if (t < C_) tokmap[b * C_ + t] = st[t];

  bool used = (t < S_) && (s < e);
  unsigned long long mset = __ballot(used);
  int lane = t & 63;
  int r = __popcll(mset & ((1ull << lane) - 1ull));
  int wcnt = __popcll(mset);
  if (t == 0) c0 = wcnt;
  __syncthreads();
  int rank = r + ((t >> 6) == 1 ? c0 : 0);
  if (t < S_) cidx[b * S_ + t] = used ? rank : -1;
  if (t == 64) cnt[b] = c0 + wcnt;
}

// ---- exclusive scan of 96 batch counts ----
__global__ void scan_kernel(const int* __restrict__ cnt, int* __restrict__ boff,
                            int* __restrict__ mc) {
  __shared__ int sc[B_];
  int t = threadIdx.x;   // 128
  if (t < B_) sc[t] = cnt[t];
  __syncthreads();
  if (t == 0) {
    int acc = 0;
    for (int i = 0; i < B_; ++i) { int v = sc[i]; sc[i] = acc; acc += v; }
    mc[0] = acc;                    // Mc: total used rows
    mc[1] = (acc + 255) >> 8;       // number of 256-row m-tiles
  }
  __syncthreads();
  if (t < B_) boff[t] = sc[t];
}

// ---- pack A (compact) + pack W + zerofill uncovered rows, one launch ----
__global__ void pack_kernel(const float* __restrict__ h0,
                            const float* __restrict__ h1,
                            const float* __restrict__ W,
                            const int* __restrict__ boff,
                            const int* __restrict__ cidx,
                            const int* __restrict__ tokmap,
                            u16* __restrict__ Ap, u16* __restrict__ Wp,
                            int* __restrict__ rowinfo,
                            float* __restrict__ out) {
  const int blk = blockIdx.x;
  const int t = threadIdx.x;      // 0..191
  if (blk < B_ * S_) {
    const int i = blk;            // b*S + tok
    int r = cidx[i];
    if (r < 0) return;
    const int b = i >> 7;
    const int dst = boff[b] + r;
    if (t == 0) rowinfo[dst] = i;
    const float4* src = (t < 96)
        ? ((const float4*)(h0 + (size_t)i * D_)) + 2 * t
        : ((const float4*)(h1 + (size_t)i * D_)) + 2 * (t - 96);
    float4 v0 = src[0], v1 = src[1];
    ushort4 o0, o1;
    o0.x = f2bf(v0.x); o0.y = f2bf(v0.y); o0.z = f2bf(v0.z); o0.w = f2bf(v0.w);
    o1.x = f2bf(v1.x); o1.y = f2bf(v1.y); o1.z = f2bf(v1.z); o1.w = f2bf(v1.w);
    ushort4* dp = (ushort4*)(Ap + (size_t)dst * K_ + 8 * t);
    dp[0] = o0; dp[1] = o1;
  } else if (blk < B_ * S_ + 3072) {
    int idx = (blk - B_ * S_) * 192 + t;   // f4 index into W (total 589824)
    float4 v = ((const float4*)W)[idx];
    ushort4 o;
    o.x = f2bf(v.x); o.y = f2bf(v.y); o.z = f2bf(v.z); o.w = f2bf(v.w);
    ((ushort4*)Wp)[idx] = o;
  } else {
    int bc = blk - (B_ * S_ + 3072);       // 0..B_*C_-1
    if (tokmap[bc] >= 0) return;
    float4 z = {0.f, 0.f, 0.f, 0.f};
    float4* o4 = (float4*)out;
    size_t base = (size_t)bc * 192;        // 192 f4 per (b,c) row
    size_t half4 = (size_t)B_ * C_ * 192;
    o4[base + t] = z;
    o4[half4 + base + t] = z;
  }
}

// ---- GEMM + fused scatter epilogue, 256x256 tile ----
// Traffic-minimizing tile (203 MB vs 396 MB at 128x128 — the L3-BW lever).
// 8 waves (2x4), BK=64 double-buffered (128 KB LDS), round-7 protocol:
// STAGE(next); vmcnt(8); barrier A; asm ds_read; lgkm0; barrier B; MFMA.
__global__ void __launch_bounds__(512, 2) gemm_kernel(
    const u16* __restrict__ A, const u16* __restrict__ Wt,
    const float* __restrict__ bias, const int* __restrict__ mc,
    const int* __restrict__ rowinfo, const int* __restrict__ om,
    float* __restrict__ out) {
  // runtime-balanced XCD-chunked swizzle over active tiles
  const int id = blockIdx.y * 6 + blockIdx.x;    // 0..287
  const int active = mc[1] * 6;
  const int cpx = (active + 7) >> 3;
  const int xcd = id & 7, slot = id >> 3;
  if (slot >= cpx) return;
  const int w = xcd * cpx + slot;
  if (w >= active) return;
  const int mtile = w / 6, ntile = w - mtile * 6;
  const int n0 = ntile * 256;
  const int m0 = mtile * 256;

  // 2 buffers x (A 32KB + B 32KB) = 128 KB; epilogue reuses base
  __shared__ char smem[131072];
  const int t = threadIdx.x;
  const int lane = t & 63;
  const int wid = t >> 6;          // 0..7
  const int wr = wid >> 2;         // 0..1 (row half: 128 rows)
  const int wc = wid & 3;          // 0..3 (col quarter: 64 cols)
  const int lr = lane & 15;
  const int lk = lane >> 4;

  f32x4 acc[8][4];
#pragma unroll
  for (int i = 0; i < 8; ++i)
#pragma unroll
    for (int j = 0; j < 4; ++j) acc[i][j] = (f32x4){0.f, 0.f, 0.f, 0.f};

  // --- staging geometry: row = 128B = 8 chunks of 16B, LDS linear.
  // wave wid, instr j covers rows j*64 + wid*8 + rsub; source chunk
  // pre-swizzled c = slot ^ (row&7)  (rule #21 both-sides swizzle).
  const int rsub = lane >> 3;                  // 0..7
  const int csw = ((lane & 7) ^ rsub) * 8;     // element offset in 64-elem row
  const u16* pa[4]; const u16* pb[4];
#pragma unroll
  for (int j = 0; j < 4; ++j) {
    pa[j] = A  + (size_t)(m0 + j * 64 + wid * 8 + rsub) * K_ + csw;
    pb[j] = Wt + (size_t)(n0 + j * 64 + wid * 8 + rsub) * K_ + csw;
  }

#define STAGE(buf, kk) do {                                            \
    char* sb_ = smem + (buf) * 65536;                                  \
    _Pragma("unroll")                                                  \
    for (int j = 0; j < 4; ++j) {                                      \
      gload_lds16(pa[j] + (kk), sb_ + (j * 64 + wid * 8) * 128);       \
      gload_lds16(pb[j] + (kk), sb_ + 32768 + (j * 64 + wid * 8) * 128); \
    }                                                                  \
  } while (0)

  // --- read offsets (XOR-swizzled within 128B row) ---
  const unsigned l0 = lds_off(smem);
  unsigned aoff[8][2], boff4[4][2];
#pragma unroll
  for (int mt = 0; mt < 8; ++mt)
#pragma unroll
    for (int ks = 0; ks < 2; ++ks) {
      unsigned colb = (unsigned)((ks * 64 + lk * 16) ^ ((lr & 7) << 4));
      aoff[mt][ks] = (unsigned)((wr * 128 + mt * 16 + lr) * 128) + colb;
      if (mt < 4)
        boff4[mt][ks] = 32768u + (unsigned)((wc * 64 + mt * 16 + lr) * 128) + colb;
    }

  STAGE(0, 0);                            // 8 outstanding (tile 0)
  const int NT = K_ / 64;                 // 24
  for (int it = 0; it < NT; ++it) {
    if (it + 1 < NT) {
      STAGE((it + 1) & 1, (it + 1) * 64); // 16 outstanding
      asm volatile("s_waitcnt vmcnt(8)" ::: "memory");   // my tile-it loads done
    } else {
      asm volatile("s_waitcnt vmcnt(0)" ::: "memory");
    }
    __builtin_amdgcn_s_barrier();         // A: ALL waves' tile-it loads landed
    const unsigned bufo = l0 + (unsigned)((it & 1) * 65536);
    bf16x8 af[8], bfr[4];
    // ks = 0
#pragma unroll
    for (int mt = 0; mt < 8; ++mt) af[mt] = ldsr128(bufo + aoff[mt][0]);
#pragma unroll
    for (int nt = 0; nt < 4; ++nt) bfr[nt] = ldsr128(bufo + boff4[nt][0]);
    asm volatile("s_waitcnt lgkmcnt(0)" ::: "memory");
    __builtin_amdgcn_sched_barrier(0);
#pragma unroll
    for (int mt = 0; mt < 8; ++mt)
#pragma unroll
      for (int nt = 0; nt < 4; ++nt)
        acc[mt][nt] = __builtin_amdgcn_mfma_f32_16x16x32_bf16(
            af[mt], bfr[nt], acc[mt][nt], 0, 0, 0);
    // ks = 1 (reuse frag registers)
#pragma unroll
    for (int mt = 0; mt < 8; ++mt) af[mt] = ldsr128(bufo + aoff[mt][1]);
#pragma unroll
    for (int nt = 0; nt < 4; ++nt) bfr[nt] = ldsr128(bufo + boff4[nt][1]);
    asm volatile("s_waitcnt lgkmcnt(0)" ::: "memory");
    __builtin_amdgcn_sched_barrier(0);
    __builtin_amdgcn_s_barrier();         // B: reads retired -> next STAGE safe
    __builtin_amdgcn_sched_barrier(0);
#pragma unroll
    for (int mt = 0; mt < 8; ++mt)
#pragma unroll
      for (int nt = 0; nt < 4; ++nt)
        acc[mt][nt] = __builtin_amdgcn_mfma_f32_16x16x32_bf16(
            af[mt], bfr[nt], acc[mt][nt], 0, 0, 0);
  }
#undef STAGE

  // ---- epilogue: per-wr-group LDS transpose (32 rows x 260 f32) + scatter ----
  const int Mc = mc[0];
  const size_t half = (size_t)B_ * C_ * D_;
  const size_t colbase = (n0 < D_) ? (size_t)n0 : (size_t)(n0 - D_) + half;
  float bn[4];
#pragma unroll
  for (int nt = 0; nt < 4; ++nt) bn[nt] = bias[n0 + wc * 64 + nt * 16 + lr];

  float* tbf = (float*)smem;          // two regions of 32*260 f32 (33280 B each)
  const int g = t >> 8;               // 0/1: scatter group == wr of waves 0-3/4-7
  const int tt = t & 255;
  const int rrow = tt >> 3;           // 0..31
  const int ck = tt & 7;              // 8 col-chunks of 32 f32

#pragma unroll
  for (int u = 0; u < 4; ++u) {       // 4 chunks of 32 rows per wr-group
    __syncthreads();                  // prev chunk's reads done
#pragma unroll
    for (int h = 0; h < 2; ++h) {     // mt = 2u+h
      int mt = 2 * u + h;
#pragma unroll
      for (int nt = 0; nt < 4; ++nt)
#pragma unroll
        for (int r = 0; r < 4; ++r)
          tbf[wr * 8320 + (h * 16 + lk * 4 + r) * 260 + wc * 64 + nt * 16 + lr] =
              acc[mt][nt][r] + bn[nt];
    }
    __syncthreads();
    int gm = m0 + g * 128 + u * 32 + rrow;
    if (gm < Mc) {
      int i = rowinfo[gm];
      int bb = i >> 7;                // / S_
      int s = om[2 * i], e = om[2 * i + 1];
      const float4* src4 = (const float4*)(tbf + g * 8320 + rrow * 260 + ck * 32);
      float4 v[8];
#pragma unroll
      for (int j = 0; j < 8; ++j) v[j] = src4[(j + rrow) & 7];   // bank-rotate
      for (int c = s; c < e; ++c) {
        float4* dst4 = (float4*)(out + (size_t)(bb * C_ + c) * D_ + colbase + ck * 32);
#pragma unroll
        for (int j = 0; j < 8; ++j) dst4[(j + rrow) & 7] = v[j];
      }
    }
  }
}

extern "C" void kernel_launch(void* const* d_in, const int* in_sizes, int n_in,
                              void* d_out, int out_size, void* d_ws, size_t ws_size,
                              hipStream_t stream) {
  (void)in_sizes; (void)n_in; (void)out_size; (void)ws_size;
  const float* h0 = (const float*)d_in[0];
  const float* h1 = (const float*)d_in[1];
  const float* W  = (const float*)d_in[2];
  const float* bias = (const float*)d_in[3];
  const int* om = (const int*)d_in[4];

  char* ws = (char*)d_ws;
  u16* Ap = (u16*)(ws);                   // 37,748,736 B (worst case)
  u16* Wp = (u16*)(ws + 37748736);        //  4,718,592 B
  int* rowinfo = (int*)(ws + 42467328);   //     49,152 B
  int* tokmap  = (int*)(ws + 42516480);   //     54,144 B
  int* cidx    = (int*)(ws + 42570624);   //     49,152 B
  int* cnt     = (int*)(ws + 42619776);   //        384 B
  int* boff    = (int*)(ws + 42620160);   //        384 B
  int* mc      = (int*)(ws + 42620544);   //         16 B
  float* out = (float*)d_out;

  tokmap_rank_kernel<<<B_, 192, 0, stream>>>(om, tokmap, cidx, cnt);
  scan_kernel<<<1, 128, 0, stream>>>(cnt, boff, mc);
  pack_kernel<<<B_ * S_ + 3072 + B_ * C_, 192, 0, stream>>>(
      h0, h1, W, boff, cidx, tokmap, Ap, Wp, rowinfo, out);
  gemm_kernel<<<dim3(6, 48), 512, 0, stream>>>(Ap, Wp, bias, mc,
                                               rowinfo, om, out);
}

// Round 9
// 98.973 us; speedup vs baseline: 1.0076x; 1.0076x over previous
//
#include <hip/hip_runtime.h>

#define B_ 96
#define S_ 128
#define C_ 141
#define D_ 768
#define K_ 1536   // 2*D
#define M_ (B_*S_)   // 12288 (worst case)
#define N_ 1536   // 2*D

typedef unsigned short u16;
typedef __bf16 bf16x8 __attribute__((ext_vector_type(8)));
typedef float f32x4 __attribute__((ext_vector_type(4)));

__device__ __forceinline__ u16 f2bf(float x) {
  unsigned int u = __float_as_uint(x);
  u = u + 0x7fffu + ((u >> 16) & 1u);   // RNE
  return (u16)(u >> 16);
}

__device__ __forceinline__ void gload_lds16(const void* g, void* l) {
  __builtin_amdgcn_global_load_lds(
      (const __attribute__((address_space(1))) unsigned int*)g,
      (__attribute__((address_space(3))) unsigned int*)l, 16, 0, 0);
}

// ---- tokmap + per-batch used-token rank (one block per batch, 192 thr) ----
__global__ void tokmap_rank_kernel(const int* __restrict__ om,
                                   int* __restrict__ tokmap,
                                   int* __restrict__ cidx,
                                   int* __restrict__ cnt) {
  __shared__ int st[C_];
  __shared__ int c0;
  const int b = blockIdx.x;
  const int t = threadIdx.x;   // 0..191
  int s = 0, e = 0;
  if (t < S_) {
    s = om[(b * S_ + t) * 2 + 0];
    e = om[(b * S_ + t) * 2 + 1];
  }
  if (t < C_) st[t] = -1;
  __syncthreads();
  if (t < S_) {
    for (int c = s; c < e; ++c) st[c] = t;   // disjoint -> race-free
  }
  __syncthreads();
  if (t < C_) tokmap[b * C_ + t] = st[t];

  bool used = (t < S_) && (s < e);
  unsigned long long mset = __ballot(used);
  int lane = t & 63;
  int r = __popcll(mset & ((1ull << lane) - 1ull));
  int wcnt = __popcll(mset);
  if (t == 0) c0 = wcnt;
  __syncthreads();
  int rank = r + ((t >> 6) == 1 ? c0 : 0);
  if (t < S_) cidx[b * S_ + t] = used ? rank : -1;
  if (t == 64) cnt[b] = c0 + wcnt;
}

// ---- exclusive scan of 96 batch counts ----
__global__ void scan_kernel(const int* __restrict__ cnt, int* __restrict__ boff,
                            int* __restrict__ mc) {
  __shared__ int sc[B_];
  int t = threadIdx.x;   // 128
  if (t < B_) sc[t] = cnt[t];
  __syncthreads();
  if (t == 0) {
    int acc = 0;
    for (int i = 0; i < B_; ++i) { int v = sc[i]; sc[i] = acc; acc += v; }
    mc[0] = acc;                    // Mc: total used rows
    mc[1] = (acc + 127) >> 7;       // number of 128-row m-tiles
  }
  __syncthreads();
  if (t < B_) boff[t] = sc[t];
}

// ---- pack A (compact) + pack W + zerofill uncovered rows, one launch ----
__global__ void pack_kernel(const float* __restrict__ h0,
                            const float* __restrict__ h1,
                            const float* __restrict__ W,
                            const int* __restrict__ boff,
                            const int* __restrict__ cidx,
                            const int* __restrict__ tokmap,
                            u16* __restrict__ Ap, u16* __restrict__ Wp,
                            int* __restrict__ rowinfo,
                            float* __restrict__ out) {
  const int blk = blockIdx.x;
  const int t = threadIdx.x;      // 0..191
  if (blk < B_ * S_) {
    const int i = blk;            // b*S + tok
    int r = cidx[i];
    if (r < 0) return;
    const int b = i >> 7;
    const int dst = boff[b] + r;
    if (t == 0) rowinfo[dst] = i;
    const float4* src = (t < 96)
        ? ((const float4*)(h0 + (size_t)i * D_)) + 2 * t
        : ((const float4*)(h1 + (size_t)i * D_)) + 2 * (t - 96);
    float4 v0 = src[0], v1 = src[1];
    ushort4 o0, o1;
    o0.x = f2bf(v0.x); o0.y = f2bf(v0.y); o0.z = f2bf(v0.z); o0.w = f2bf(v0.w);
    o1.x = f2bf(v1.x); o1.y = f2bf(v1.y); o1.z = f2bf(v1.z); o1.w = f2bf(v1.w);
    ushort4* dp = (ushort4*)(Ap + (size_t)dst * K_ + 8 * t);
    dp[0] = o0; dp[1] = o1;
  } else if (blk < B_ * S_ + 3072) {
    int idx = (blk - B_ * S_) * 192 + t;   // f4 index into W (total 589824)
    float4 v = ((const float4*)W)[idx];
    ushort4 o;
    o.x = f2bf(v.x); o.y = f2bf(v.y); o.z = f2bf(v.z); o.w = f2bf(v.w);
    ((ushort4*)Wp)[idx] = o;
  } else {
    int bc = blk - (B_ * S_ + 3072);       // 0..B_*C_-1
    if (tokmap[bc] >= 0) return;
    float4 z = {0.f, 0.f, 0.f, 0.f};
    float4* o4 = (float4*)out;
    size_t base = (size_t)bc * 192;        // 192 f4 per (b,c) row
    size_t half4 = (size_t)B_ * C_ * 192;
    o4[base + t] = z;
    o4[half4 + base + t] = z;
  }
}

// ---- GEMM + fused scatter epilogue ----
// BK=128, SINGLE buffer, COMPILER-scheduled loop (the R3 empirical winner):
// sync; STAGE; sync; compute. 12 iters instead of 48 amortizes the
// vmcnt(0)-drain fixed cost 4x; 2 blocks/CU give implicit overlap (m114).
// Source-side XOR swizzle + swizzled reads keep ds_read_b128 2-way max.
__global__ void __launch_bounds__(256) gemm_kernel(
    const u16* __restrict__ A, const u16* __restrict__ Wt,
    const float* __restrict__ bias, const int* __restrict__ mc,
    const int* __restrict__ rowinfo, const int* __restrict__ om,
    float* __restrict__ out) {
  // runtime-balanced XCD-chunked swizzle
  const int id = blockIdx.y * 12 + blockIdx.x;   // 0..1151
  const int active = mc[1] * 12;
  const int cpx = (active + 7) >> 3;
  const int xcd = id & 7, slot = id >> 3;
  if (slot >= cpx) return;
  const int w = xcd * cpx + slot;
  if (w >= active) return;
  const int mtile = w / 12, ntile = w - mtile * 12;
  const int n0 = ntile * 128;
  const int m0 = mtile * 128;

  // A 32KB + B 32KB single buffer; epilogue transpose reuses base
  __shared__ char smem[65536];
  u16* As = (u16*)smem;
  u16* Bs = (u16*)(smem + 32768);
  const int t = threadIdx.x;
  const int lane = t & 63;
  const int wid = t >> 6;
  const int wm = wid >> 1;
  const int wn = wid & 1;
  const int lr = lane & 15;
  const int lk = lane >> 4;

  f32x4 acc[4][4];
#pragma unroll
  for (int i = 0; i < 4; ++i)
#pragma unroll
    for (int j = 0; j < 4; ++j) acc[i][j] = (f32x4){0.f, 0.f, 0.f, 0.f};

  // --- staging geometry (BK=128: row = 256B = 16 chunks of 16B) ---
  // wave wid instr j: linear dest window (wid*8+j)*1024, lane l -> row
  // (wid*8+j)*4 + (l>>4), stored chunk position l&15. Source fetches the
  // logical chunk c = (l&15) ^ (r&15)  (rule #21: inverse-swizzled source).
  int aoff[8];
#pragma unroll
  for (int j = 0; j < 8; ++j) {
    int r = (wid * 8 + j) * 4 + (lane >> 4);
    int c = (lane & 15) ^ (r & 15);
    aoff[j] = r * K_ + c * 8;            // element offset within panel
  }
  const u16* Abase = A + (size_t)m0 * K_;
  const u16* Bbase = Wt + (size_t)n0 * K_;

  // --- read swizzle: frag (ks,lk) of row r lives at chunk (ks*4+lk)^(r&15);
  // rows here have r&15 == lr for all fragments.
  int cs[4];
#pragma unroll
  for (int ks = 0; ks < 4; ++ks) cs[ks] = (((ks * 4 + lk) ^ lr)) * 8;
  int arow[4], brow[4];
#pragma unroll
  for (int i = 0; i < 4; ++i) {
    arow[i] = (wm * 64 + i * 16 + lr) * 128;
    brow[i] = (wn * 64 + i * 16 + lr) * 128;
  }

  for (int kk = 0; kk < K_; kk += 128) {
    __syncthreads();                     // prev iter's LDS reads done
#pragma unroll
    for (int j = 0; j < 8; ++j) {
      gload_lds16(Abase + aoff[j] + kk, smem + (wid * 8 + j) * 1024);
      gload_lds16(Bbase + aoff[j] + kk, smem + 32768 + (wid * 8 + j) * 1024);
    }
    __syncthreads();                     // compiler drains vmcnt: tile landed
#pragma unroll
    for (int ks = 0; ks < 4; ++ks) {
      bf16x8 af[4], bfr[4];
#pragma unroll
      for (int mt = 0; mt < 4; ++mt)
        af[mt] = *(const bf16x8*)(As + arow[mt] + cs[ks]);
#pragma unroll
      for (int nt = 0; nt < 4; ++nt)
        bfr[nt] = *(const bf16x8*)(Bs + brow[nt] + cs[ks]);
#pragma unroll
      for (int mt = 0; mt < 4; ++mt)
#pragma unroll
        for (int nt = 0; nt < 4; ++nt)
          acc[mt][nt] = __builtin_amdgcn_mfma_f32_16x16x32_bf16(
              af[mt], bfr[nt], acc[mt][nt], 0, 0, 0);
    }
  }

  // ---- epilogue: LDS transpose (32 rows x 132 f32, +4 pad) + wide scatter ----
  const int Mc = mc[0];
  const size_t half = (size_t)B_ * C_ * D_;
  const size_t colbase = (n0 < D_) ? (size_t)n0 : (size_t)(n0 - D_) + half;
  float bn[4];
#pragma unroll
  for (int nt = 0; nt < 4; ++nt) bn[nt] = bias[n0 + wn * 64 + nt * 16 + lr];

  float* tb = (float*)smem;           // 32*132*4 = 16896 B
  const int rrow = t >> 3;            // 0..31
  const int rcol = (t & 7) * 16;      // 0,16,..,112
  const int gmbase = m0 + (rrow >> 4) * 64 + (rrow & 15);

#pragma unroll
  for (int mt = 0; mt < 4; ++mt) {
    __syncthreads();                  // K-loop done / prev mt reads done
#pragma unroll
    for (int nt = 0; nt < 4; ++nt)
#pragma unroll
      for (int r = 0; r < 4; ++r)
        tb[(wm * 16 + lk * 4 + r) * 132 + wn * 64 + nt * 16 + lr] =
            acc[mt][nt][r] + bn[nt];
    __syncthreads();
    int gm = gmbase + mt * 16;
    if (gm < Mc) {
      int i = rowinfo[gm];
      int bb = i >> 7;                // / S_
      int s = om[2 * i], e = om[2 * i + 1];
      const float* src = tb + rrow * 132 + rcol;
      float4 v0 = *(const float4*)(src);
      float4 v1 = *(const float4*)(src + 4);
      float4 v2 = *(const float4*)(src + 8);
      float4 v3 = *(const float4*)(src + 12);
      for (int c = s; c < e; ++c) {
        float* dst = out + (size_t)(bb * C_ + c) * D_ + colbase + rcol;
        ((float4*)dst)[0] = v0;
        ((float4*)dst)[1] = v1;
        ((float4*)dst)[2] = v2;
        ((float4*)dst)[3] = v3;
      }
    }
  }
}

extern "C" void kernel_launch(void* const* d_in, const int* in_sizes, int n_in,
                              void* d_out, int out_size, void* d_ws, size_t ws_size,
                              hipStream_t stream) {
  (void)in_sizes; (void)n_in; (void)out_size; (void)ws_size;
  const float* h0 = (const float*)d_in[0];
  const float* h1 = (const float*)d_in[1];
  const float* W  = (const float*)d_in[2];
  const float* bias = (const float*)d_in[3];
  const int* om = (const int*)d_in[4];

  char* ws = (char*)d_ws;
  u16* Ap = (u16*)(ws);                   // 37,748,736 B (worst case)
  u16* Wp = (u16*)(ws + 37748736);        //  4,718,592 B
  int* rowinfo = (int*)(ws + 42467328);   //     49,152 B
  int* tokmap  = (int*)(ws + 42516480);   //     54,144 B
  int* cidx    = (int*)(ws + 42570624);   //     49,152 B
  int* cnt     = (int*)(ws + 42619776);   //        384 B
  int* boff    = (int*)(ws + 42620160);   //        384 B
  int* mc      = (int*)(ws + 42620544);   //         16 B
  float* out = (float*)d_out;

  tokmap_rank_kernel<<<B_, 192, 0, stream>>>(om, tokmap, cidx, cnt);
  scan_kernel<<<1, 128, 0, stream>>>(cnt, boff, mc);
  pack_kernel<<<B_ * S_ + 3072 + B_ * C_, 192, 0, stream>>>(
      h0, h1, W, boff, cidx, tokmap, Ap, Wp, rowinfo, out);
  gemm_kernel<<<dim3(12, 96), 256, 0, stream>>>(Ap, Wp, bias, mc,
                                                rowinfo, om, out);
}

// Round 10
// 91.940 us; speedup vs baseline: 1.0847x; 1.0765x over previous
//
#include <hip/hip_runtime.h>

#define B_ 96
#define S_ 128
#define C_ 141
#define D_ 768
#define K_ 1536   // 2*D
#define M_ (B_*S_)   // 12288 (worst case)
#define N_ 1536   // 2*D

typedef unsigned short u16;
typedef __bf16 bf16x8 __attribute__((ext_vector_type(8)));
typedef float f32x4 __attribute__((ext_vector_type(4)));

__device__ __forceinline__ u16 f2bf(float x) {
  unsigned int u = __float_as_uint(x);
  u = u + 0x7fffu + ((u >> 16) & 1u);   // RNE
  return (u16)(u >> 16);
}

__device__ __forceinline__ void gload_lds16(const void* g, void* l) {
  __builtin_amdgcn_global_load_lds(
      (const __attribute__((address_space(1))) unsigned int*)g,
      (__attribute__((address_space(3))) unsigned int*)l, 16, 0, 0);
}

// ---- tokmap + per-batch used-token rank (one block per batch, 192 thr) ----
__global__ void tokmap_rank_kernel(const int* __restrict__ om,
                                   int* __restrict__ tokmap,
                                   int* __restrict__ cidx,
                                   int* __restrict__ cnt) {
  __shared__ int st[C_];
  __shared__ int c0;
  const int b = blockIdx.x;
  const int t = threadIdx.x;   // 0..191
  int s = 0, e = 0;
  if (t < S_) {
    s = om[(b * S_ + t) * 2 + 0];
    e = om[(b * S_ + t) * 2 + 1];
  }
  if (t < C_) st[t] = -1;
  __syncthreads();
  if (t < S_) {
    for (int c = s; c < e; ++c) st[c] = t;   // disjoint -> race-free
  }
  __syncthreads();
  if (t < C_) tokmap[b * C_ + t] = st[t];

  bool used = (t < S_) && (s < e);
  unsigned long long mset = __ballot(used);
  int lane = t & 63;
  int r = __popcll(mset & ((1ull << lane) - 1ull));
  int wcnt = __popcll(mset);
  if (t == 0) c0 = wcnt;
  __syncthreads();
  int rank = r + ((t >> 6) == 1 ? c0 : 0);
  if (t < S_) cidx[b * S_ + t] = used ? rank : -1;
  if (t == 64) cnt[b] = c0 + wcnt;
}

// ---- exclusive scan of 96 batch counts ----
__global__ void scan_kernel(const int* __restrict__ cnt, int* __restrict__ boff,
                            int* __restrict__ mc) {
  __shared__ int sc[B_];
  int t = threadIdx.x;   // 128
  if (t < B_) sc[t] = cnt[t];
  __syncthreads();
  if (t == 0) {
    int acc = 0;
    for (int i = 0; i < B_; ++i) { int v = sc[i]; sc[i] = acc; acc += v; }
    mc[0] = acc;                    // Mc: total used rows
    mc[1] = (acc + 127) >> 7;       // number of 128-row m-tiles
  }
  __syncthreads();
  if (t < B_) boff[t] = sc[t];
}

// ---- pack A (compact) + pack W + zerofill uncovered rows, one launch ----
__global__ void pack_kernel(const float* __restrict__ h0,
                            const float* __restrict__ h1,
                            const float* __restrict__ W,
                            const int* __restrict__ boff,
                            const int* __restrict__ cidx,
                            const int* __restrict__ tokmap,
                            u16* __restrict__ Ap, u16* __restrict__ Wp,
                            int* __restrict__ rowinfo,
                            float* __restrict__ out) {
  const int blk = blockIdx.x;
  const int t = threadIdx.x;      // 0..191
  if (blk < B_ * S_) {
    const int i = blk;            // b*S + tok
    int r = cidx[i];
    if (r < 0) return;
    const int b = i >> 7;
    const int dst = boff[b] + r;
    if (t == 0) rowinfo[dst] = i;
    const float4* src = (t < 96)
        ? ((const float4*)(h0 + (size_t)i * D_)) + 2 * t
        : ((const float4*)(h1 + (size_t)i * D_)) + 2 * (t - 96);
    float4 v0 = src[0], v1 = src[1];
    ushort4 o0, o1;
    o0.x = f2bf(v0.x); o0.y = f2bf(v0.y); o0.z = f2bf(v0.z); o0.w = f2bf(v0.w);
    o1.x = f2bf(v1.x); o1.y = f2bf(v1.y); o1.z = f2bf(v1.z); o1.w = f2bf(v1.w);
    ushort4* dp = (ushort4*)(Ap + (size_t)dst * K_ + 8 * t);
    dp[0] = o0; dp[1] = o1;
  } else if (blk < B_ * S_ + 3072) {
    int idx = (blk - B_ * S_) * 192 + t;   // f4 index into W (total 589824)
    float4 v = ((const float4*)W)[idx];
    ushort4 o;
    o.x = f2bf(v.x); o.y = f2bf(v.y); o.z = f2bf(v.z); o.w = f2bf(v.w);
    ((ushort4*)Wp)[idx] = o;
  } else {
    int bc = blk - (B_ * S_ + 3072);       // 0..B_*C_-1
    if (tokmap[bc] >= 0) return;
    float4 z = {0.f, 0.f, 0.f, 0.f};
    float4* o4 = (float4*)out;
    size_t base = (size_t)bc * 192;        // 192 f4 per (b,c) row
    size_t half4 = (size_t)B_ * C_ * 192;
    o4[base + t] = z;
    o4[half4 + base + t] = z;
  }
}

// ---- GEMM + fused scatter epilogue ----
// R3's proven K-loop: BK=32, 16 KB LDS, two __syncthreads per iter,
// compiler-scheduled loads/reads (NO asm, NO explicit pipelining).
// Minimal LDS => ~5 blocks/CU resident => all 516 active blocks co-resident,
// no round-quantization tail (the R4-R9 regression mechanism).
// Epilogue: wave-local LDS transpose (no barriers) + 256B-segment stores.
__global__ void __launch_bounds__(256) gemm_kernel(
    const u16* __restrict__ A, const u16* __restrict__ Wt,
    const float* __restrict__ bias, const int* __restrict__ mc,
    const int* __restrict__ rowinfo, const int* __restrict__ om,
    float* __restrict__ out) {
  // runtime-balanced XCD-chunked swizzle
  const int id = blockIdx.y * 12 + blockIdx.x;   // 0..1151
  const int active = mc[1] * 12;
  const int cpx = (active + 7) >> 3;
  const int xcd = id & 7, slot = id >> 3;
  if (slot >= cpx) return;
  const int w = xcd * cpx + slot;
  if (w >= active) return;
  const int mtile = w / 12, ntile = w - mtile * 12;
  const int n0 = ntile * 128;
  const int m0 = mtile * 128;

  // K-loop: As 8KB + Bs 8KB. Epilogue reuses base as 4 wave slices of 4352B.
  __shared__ char smem[17536];
  u16* As = (u16*)smem;
  u16* Bs = (u16*)(smem + 8192);
  const int t = threadIdx.x;
  const int lane = t & 63;
  const int wid = t >> 6;
  const int wm = wid >> 1;
  const int wn = wid & 1;
  const int lr = lane & 15;
  const int lk = lane >> 4;

  f32x4 acc[4][4];
#pragma unroll
  for (int i = 0; i < 4; ++i)
#pragma unroll
    for (int j = 0; j < 4; ++j) acc[i][j] = (f32x4){0.f, 0.f, 0.f, 0.f};

  const int rowc = t >> 2;
  const int koff = (t & 3) * 8;
  const size_t ga0 = (size_t)(m0 + rowc) * K_ + koff;
  const size_t ga1 = (size_t)(m0 + 64 + rowc) * K_ + koff;
  const size_t gb0 = (size_t)(n0 + rowc) * K_ + koff;
  const size_t gb1 = (size_t)(n0 + 64 + rowc) * K_ + koff;
  const int l0 = wid * 1024;

  for (int kk = 0; kk < K_; kk += 32) {
    __syncthreads();   // previous iter's LDS reads done before overwrite
    gload_lds16(A + ga0 + kk, (char*)As + l0);
    gload_lds16(A + ga1 + kk, (char*)As + 4096 + l0);
    gload_lds16(Wt + gb0 + kk, (char*)Bs + l0);
    gload_lds16(Wt + gb1 + kk, (char*)Bs + 4096 + l0);
    __syncthreads();   // compiler drains vmcnt before barrier: tile landed

    bf16x8 af[4], bfr[4];
#pragma unroll
    for (int mt = 0; mt < 4; ++mt)
      af[mt] = *(const bf16x8*)(As + (wm * 64 + mt * 16 + lr) * 32 + lk * 8);
#pragma unroll
    for (int nt = 0; nt < 4; ++nt)
      bfr[nt] = *(const bf16x8*)(Bs + (wn * 64 + nt * 16 + lr) * 32 + lk * 8);
#pragma unroll
    for (int mt = 0; mt < 4; ++mt)
#pragma unroll
      for (int nt = 0; nt < 4; ++nt)
        acc[mt][nt] = __builtin_amdgcn_mfma_f32_16x16x32_bf16(
            af[mt], bfr[nt], acc[mt][nt], 0, 0, 0);
  }

  // ---- epilogue: wave-local transpose slice (16 x 68 f32, 2-way max) ----
  __syncthreads();   // all waves done with As/Bs before slice overwrite
  const int Mc = mc[0];
  const size_t half = (size_t)B_ * C_ * D_;
  // 128-col tiles never straddle the D_ boundary
  const size_t colbase = ((n0 < D_) ? (size_t)n0 : (size_t)(n0 - D_) + half)
                         + wn * 64;
  float bn[4];
#pragma unroll
  for (int nt = 0; nt < 4; ++nt) bn[nt] = bias[n0 + wn * 64 + nt * 16 + lr];

  float* slice = (float*)smem + wid * 1088;   // 4352 B per wave
  const int rl = lane >> 2;    // 0..15: local row this lane scatters
  const int q = lane & 3;      // 64B quarter of the 256B half-row

#pragma unroll
  for (int mt = 0; mt < 4; ++mt) {
    // wave-internal LDS ordering: compiler inserts lgkm waits; no barrier.
#pragma unroll
    for (int nt = 0; nt < 4; ++nt)
#pragma unroll
      for (int r = 0; r < 4; ++r)
        slice[(lk * 4 + r) * 68 + nt * 16 + lr] = acc[mt][nt][r] + bn[nt];
    int gm = m0 + wm * 64 + mt * 16 + rl;
    if (gm < Mc) {
      int i = rowinfo[gm];
      int bb = i >> 7;                // / S_
      int s = om[2 * i], e = om[2 * i + 1];
      const float* src = slice + rl * 68 + q * 16;
      float4 v0 = *(const float4*)(src);
      float4 v1 = *(const float4*)(src + 4);
      float4 v2 = *(const float4*)(src + 8);
      float4 v3 = *(const float4*)(src + 12);
      for (int c = s; c < e; ++c) {
        float* dst = out + (size_t)(bb * C_ + c) * D_ + colbase + q * 16;
        ((float4*)dst)[0] = v0;
        ((float4*)dst)[1] = v1;
        ((float4*)dst)[2] = v2;
        ((float4*)dst)[3] = v3;
      }
    }
  }
}

extern "C" void kernel_launch(void* const* d_in, const int* in_sizes, int n_in,
                              void* d_out, int out_size, void* d_ws, size_t ws_size,
                              hipStream_t stream) {
  (void)in_sizes; (void)n_in; (void)out_size; (void)ws_size;
  const float* h0 = (const float*)d_in[0];
  const float* h1 = (const float*)d_in[1];
  const float* W  = (const float*)d_in[2];
  const float* bias = (const float*)d_in[3];
  const int* om = (const int*)d_in[4];

  char* ws = (char*)d_ws;
  u16* Ap = (u16*)(ws);                   // 37,748,736 B (worst case)
  u16* Wp = (u16*)(ws + 37748736);        //  4,718,592 B
  int* rowinfo = (int*)(ws + 42467328);   //     49,152 B
  int* tokmap  = (int*)(ws + 42516480);   //     54,144 B
  int* cidx    = (int*)(ws + 42570624);   //     49,152 B
  int* cnt     = (int*)(ws + 42619776);   //        384 B
  int* boff    = (int*)(ws + 42620160);   //        384 B
  int* mc      = (int*)(ws + 42620544);   //         16 B
  float* out = (float*)d_out;

  tokmap_rank_kernel<<<B_, 192, 0, stream>>>(om, tokmap, cidx, cnt);
  scan_kernel<<<1, 128, 0, stream>>>(cnt, boff, mc);
  pack_kernel<<<B_ * S_ + 3072 + B_ * C_, 192, 0, stream>>>(
      h0, h1, W, boff, cidx, tokmap, Ap, Wp, rowinfo, out);
  gemm_kernel<<<dim3(12, 96), 256, 0, stream>>>(Ap, Wp, bias, mc,
                                                rowinfo, om, out);
}

// Round 11
// 88.793 us; speedup vs baseline: 1.1231x; 1.0354x over previous
//
#include <hip/hip_runtime.h>

#define B_ 96
#define S_ 128
#define C_ 141
#define D_ 768
#define K_ 1536   // 2*D
#define M_ (B_*S_)   // 12288 (worst case)
#define N_ 1536   // 2*D

typedef unsigned short u16;
typedef __bf16 bf16x8 __attribute__((ext_vector_type(8)));
typedef float f32x4 __attribute__((ext_vector_type(4)));

__device__ __forceinline__ u16 f2bf(float x) {
  unsigned int u = __float_as_uint(x);
  u = u + 0x7fffu + ((u >> 16) & 1u);   // RNE
  return (u16)(u >> 16);
}

__device__ __forceinline__ void gload_lds16(const void* g, void* l) {
  __builtin_amdgcn_global_load_lds(
      (const __attribute__((address_space(1))) unsigned int*)g,
      (__attribute__((address_space(3))) unsigned int*)l, 16, 0, 0);
}

// ---- tokmap + per-batch used-token rank (one block per batch, 192 thr) ----
__global__ void tokmap_rank_kernel(const int* __restrict__ om,
                                   int* __restrict__ tokmap,
                                   int* __restrict__ cidx,
                                   int* __restrict__ cnt) {
  __shared__ int st[C_];
  __shared__ int c0;
  const int b = blockIdx.x;
  const int t = threadIdx.x;   // 0..191
  int s = 0, e = 0;
  if (t < S_) {
    s = om[(b * S_ + t) * 2 + 0];
    e = om[(b * S_ + t) * 2 + 1];
  }
  if (t < C_) st[t] = -1;
  __syncthreads();
  if (t < S_) {
    for (int c = s; c < e; ++c) st[c] = t;   // disjoint -> race-free
  }
  __syncthreads();
  if (t < C_) tokmap[b * C_ + t] = st[t];

  bool used = (t < S_) && (s < e);
  unsigned long long mset = __ballot(used);
  int lane = t & 63;
  int r = __popcll(mset & ((1ull << lane) - 1ull));
  int wcnt = __popcll(mset);
  if (t == 0) c0 = wcnt;
  __syncthreads();
  int rank = r + ((t >> 6) == 1 ? c0 : 0);
  if (t < S_) cidx[b * S_ + t] = used ? rank : -1;
  if (t == 64) cnt[b] = c0 + wcnt;
}

// ---- exclusive scan of 96 batch counts ----
__global__ void scan_kernel(const int* __restrict__ cnt, int* __restrict__ boff,
                            int* __restrict__ mc) {
  __shared__ int sc[B_];
  int t = threadIdx.x;   // 128
  if (t < B_) sc[t] = cnt[t];
  __syncthreads();
  if (t == 0) {
    int acc = 0;
    for (int i = 0; i < B_; ++i) { int v = sc[i]; sc[i] = acc; acc += v; }
    mc[0] = acc;                    // Mc: total used rows
    mc[1] = (acc + 127) >> 7;       // number of 128-row m-tiles
  }
  __syncthreads();
  if (t < B_) boff[t] = sc[t];
}

// ---- pack A (compact) + pack W + zerofill uncovered rows, one launch ----
__global__ void pack_kernel(const float* __restrict__ h0,
                            const float* __restrict__ h1,
                            const float* __restrict__ W,
                            const int* __restrict__ boff,
                            const int* __restrict__ cidx,
                            const int* __restrict__ tokmap,
                            u16* __restrict__ Ap, u16* __restrict__ Wp,
                            int* __restrict__ rowinfo,
                            float* __restrict__ out) {
  const int blk = blockIdx.x;
  const int t = threadIdx.x;      // 0..191
  if (blk < B_ * S_) {
    const int i = blk;            // b*S + tok
    int r = cidx[i];
    if (r < 0) return;
    const int b = i >> 7;
    const int dst = boff[b] + r;
    if (t == 0) rowinfo[dst] = i;
    const float4* src = (t < 96)
        ? ((const float4*)(h0 + (size_t)i * D_)) + 2 * t
        : ((const float4*)(h1 + (size_t)i * D_)) + 2 * (t - 96);
    float4 v0 = src[0], v1 = src[1];
    ushort4 o0, o1;
    o0.x = f2bf(v0.x); o0.y = f2bf(v0.y); o0.z = f2bf(v0.z); o0.w = f2bf(v0.w);
    o1.x = f2bf(v1.x); o1.y = f2bf(v1.y); o1.z = f2bf(v1.z); o1.w = f2bf(v1.w);
    ushort4* dp = (ushort4*)(Ap + (size_t)dst * K_ + 8 * t);
    dp[0] = o0; dp[1] = o1;
  } else if (blk < B_ * S_ + 3072) {
    int idx = (blk - B_ * S_) * 192 + t;   // f4 index into W (total 589824)
    float4 v = ((const float4*)W)[idx];
    ushort4 o;
    o.x = f2bf(v.x); o.y = f2bf(v.y); o.z = f2bf(v.z); o.w = f2bf(v.w);
    ((ushort4*)Wp)[idx] = o;
  } else {
    int bc = blk - (B_ * S_ + 3072);       // 0..B_*C_-1
    if (tokmap[bc] >= 0) return;
    float4 z = {0.f, 0.f, 0.f, 0.f};
    float4* o4 = (float4*)out;
    size_t base = (size_t)bc * 192;        // 192 f4 per (b,c) row
    size_t half4 = (size_t)B_ * C_ * 192;
    o4[base + t] = z;
    o4[half4 + base + t] = z;
  }
}

// ---- GEMM + fused scatter epilogue ----
// R3's proven structure (best measured: 66 µs), with ONE change: n-major
// block ordering within each XCD chunk. Consecutive blocks on an XCD now
// share the W n-slice (384KB, L2-resident) AND the chunk's ~6 A-tiles
// (~2.3MB, also L2-resident) -> L3->L2 traffic ~214MB -> ~55MB.
__global__ void __launch_bounds__(256) gemm_kernel(
    const u16* __restrict__ A, const u16* __restrict__ Wt,
    const float* __restrict__ bias, const int* __restrict__ mc,
    const int* __restrict__ rowinfo, const int* __restrict__ om,
    float* __restrict__ out) {
  // runtime-balanced XCD-chunked swizzle, n-major within chunk
  const int id = blockIdx.y * 12 + blockIdx.x;   // 0..1151
  const int mtc = mc[1];                         // active m-tile count
  const int active = mtc * 12;
  const int cpx = (active + 7) >> 3;
  const int xcd = id & 7, slot = id >> 3;
  if (slot >= cpx) return;
  const int w = xcd * cpx + slot;
  if (w >= active) return;
  const int ntile = w / mtc;                     // n CONSTANT across chunk run
  const int mtile = w - ntile * mtc;             // m fastest within chunk
  const int n0 = ntile * 128;
  const int m0 = mtile * 128;

  __shared__ u16 As[128 * 32];
  __shared__ u16 Bs[128 * 32];
  const int t = threadIdx.x;
  const int lane = t & 63;
  const int wid = t >> 6;
  const int wm = wid >> 1;
  const int wn = wid & 1;
  const int lr = lane & 15;
  const int lk = lane >> 4;

  f32x4 acc[4][4];
#pragma unroll
  for (int i = 0; i < 4; ++i)
#pragma unroll
    for (int j = 0; j < 4; ++j) acc[i][j] = (f32x4){0.f, 0.f, 0.f, 0.f};

  const int rowc = t >> 2;
  const int koff = (t & 3) * 8;
  const size_t ga0 = (size_t)(m0 + rowc) * K_ + koff;
  const size_t ga1 = (size_t)(m0 + 64 + rowc) * K_ + koff;
  const size_t gb0 = (size_t)(n0 + rowc) * K_ + koff;
  const size_t gb1 = (size_t)(n0 + 64 + rowc) * K_ + koff;
  const int l0 = wid * 1024;

  for (int kk = 0; kk < K_; kk += 32) {
    __syncthreads();   // previous iter's LDS reads done before overwrite
    gload_lds16(A + ga0 + kk, (char*)As + l0);
    gload_lds16(A + ga1 + kk, (char*)As + 4096 + l0);
    gload_lds16(Wt + gb0 + kk, (char*)Bs + l0);
    gload_lds16(Wt + gb1 + kk, (char*)Bs + 4096 + l0);
    __syncthreads();   // compiler drains vmcnt: tile landed

    bf16x8 af[4], bfr[4];
#pragma unroll
    for (int mt = 0; mt < 4; ++mt)
      af[mt] = *(const bf16x8*)(As + (wm * 64 + mt * 16 + lr) * 32 + lk * 8);
#pragma unroll
    for (int nt = 0; nt < 4; ++nt)
      bfr[nt] = *(const bf16x8*)(Bs + (wn * 64 + nt * 16 + lr) * 32 + lk * 8);
#pragma unroll
    for (int mt = 0; mt < 4; ++mt)
#pragma unroll
      for (int nt = 0; nt < 4; ++nt)
        acc[mt][nt] = __builtin_amdgcn_mfma_f32_16x16x32_bf16(
            af[mt], bfr[nt], acc[mt][nt], 0, 0, 0);
  }

  // ---- epilogue: R3's exact scalar scatter (empirical best) ----
  const int Mc = mc[0];
  const size_t half = (size_t)B_ * C_ * D_;   // f32 offset of end-tensor
  float bn[4];
#pragma unroll
  for (int nt = 0; nt < 4; ++nt) bn[nt] = bias[n0 + wn * 64 + nt * 16 + lr];

#pragma unroll
  for (int mt = 0; mt < 4; ++mt) {
#pragma unroll
    for (int r = 0; r < 4; ++r) {
      int row = m0 + wm * 64 + mt * 16 + lk * 4 + r;
      if (row < Mc) {
        int i = rowinfo[row];
        int bb = i >> 7;               // / S_
        int s = om[2 * i], e = om[2 * i + 1];
#pragma unroll
        for (int nt = 0; nt < 4; ++nt) {
          int ncol = n0 + wn * 64 + nt * 16 + lr;
          float v = acc[mt][nt][r] + bn[nt];
          size_t colo = (ncol < D_) ? (size_t)ncol
                                    : (size_t)(ncol - D_) + half;
          for (int c = s; c < e; ++c)
            out[(size_t)(bb * C_ + c) * D_ + colo] = v;
        }
      }
    }
  }
}

extern "C" void kernel_launch(void* const* d_in, const int* in_sizes, int n_in,
                              void* d_out, int out_size, void* d_ws, size_t ws_size,
                              hipStream_t stream) {
  (void)in_sizes; (void)n_in; (void)out_size; (void)ws_size;
  const float* h0 = (const float*)d_in[0];
  const float* h1 = (const float*)d_in[1];
  const float* W  = (const float*)d_in[2];
  const float* bias = (const float*)d_in[3];
  const int* om = (const int*)d_in[4];

  char* ws = (char*)d_ws;
  u16* Ap = (u16*)(ws);                   // 37,748,736 B (worst case)
  u16* Wp = (u16*)(ws + 37748736);        //  4,718,592 B
  int* rowinfo = (int*)(ws + 42467328);   //     49,152 B
  int* tokmap  = (int*)(ws + 42516480);   //     54,144 B
  int* cidx    = (int*)(ws + 42570624);   //     49,152 B
  int* cnt     = (int*)(ws + 42619776);   //        384 B
  int* boff    = (int*)(ws + 42620160);   //        384 B
  int* mc      = (int*)(ws + 42620544);   //         16 B
  float* out = (float*)d_out;

  tokmap_rank_kernel<<<B_, 192, 0, stream>>>(om, tokmap, cidx, cnt);
  scan_kernel<<<1, 128, 0, stream>>>(cnt, boff, mc);
  pack_kernel<<<B_ * S_ + 3072 + B_ * C_, 192, 0, stream>>>(
      h0, h1, W, boff, cidx, tokmap, Ap, Wp, rowinfo, out);
  gemm_kernel<<<dim3(12, 96), 256, 0, stream>>>(Ap, Wp, bias, mc,
                                                rowinfo, om, out);
}